// Round 1
// baseline (1511.340 us; speedup 1.0000x reference)
//
#include <hip/hip_runtime.h>

// Problem constants
#define NB 128      // batch
#define NM 64       // sensors
#define NT 128      // snapshots
#define NG 2048     // gridpoints
#define NH 32       // hidden
// VAR_NOISE = 0.1f

// ---------------------------------------------------------------------------
// Workspace layout (floats):
//  D   [128*64*64]   off 0
//  S   [128*64*64]   off 524288   (also holds partial cov half 0 before k_inv)
//  M   [128*64*64]   off 1048576  (also holds partial cov half 1 before k_inv)
//  T1  [128*2048]    off 1572864
//  T2  [128*2048]    off 1835008
//  gA  [128*2048]    off 2097152
//  gB  [128*2048]    off 2359296
//  total 2621440 floats = 10.5 MB
// ---------------------------------------------------------------------------

__global__ __launch_bounds__(256) void k_init(float* __restrict__ g) {
    g[blockIdx.x * 256 + threadIdx.x] = 1.0f;
}

// D[b] = data[b] * data[b]^T / NT    (once per call; data constant)
__global__ __launch_bounds__(256) void k_D(const float* __restrict__ data,
                                           float* __restrict__ D) {
    __shared__ float sd[64 * 133];   // stride 133: (5*i + t) % 32 -> 2-way max
    int b = blockIdx.x, t = threadIdx.x;
    const float* db = data + (size_t)b * 8192;
    for (int idx = t; idx < 8192; idx += 256)
        sd[(idx >> 7) * 133 + (idx & 127)] = db[idx];
    __syncthreads();
    int i0 = (t & 15) * 4, j0 = (t >> 4) * 4;
    float acc[4][4];
#pragma unroll
    for (int r = 0; r < 4; ++r)
#pragma unroll
        for (int c = 0; c < 4; ++c) acc[r][c] = 0.f;
    for (int tt = 0; tt < 128; ++tt) {
        float av[4], bv[4];
#pragma unroll
        for (int r = 0; r < 4; ++r) av[r] = sd[(i0 + r) * 133 + tt];
#pragma unroll
        for (int c = 0; c < 4; ++c) bv[c] = sd[(j0 + c) * 133 + tt];
#pragma unroll
        for (int r = 0; r < 4; ++r)
#pragma unroll
            for (int c = 0; c < 4; ++c) acc[r][c] += av[r] * bv[c];
    }
    float* Db = D + (size_t)b * 4096;
#pragma unroll
    for (int r = 0; r < 4; ++r)
#pragma unroll
        for (int c = 0; c < 4; ++c)
            Db[(i0 + r) * 64 + j0 + c] = acc[r][c] * (1.0f / 128.0f);
}

// Partial covariance: block (b, half) accumulates over 1024 g's.
// half 0 -> p0 (=S buffer), half 1 -> p1 (=M buffer); summed in k_inv.
__global__ __launch_bounds__(256) void k_cov(const float* __restrict__ A,
                                             const float* __restrict__ g,
                                             float* __restrict__ p0,
                                             float* __restrict__ p1) {
    int b = blockIdx.x >> 1, half = blockIdx.x & 1, t = threadIdx.x;
    int goff = half * 1024;
    __shared__ float sA[32 * 64];    // [gg][m]  (b128-aligned reads)
    __shared__ float sAg[32 * 64];   // scaled by gamma
    __shared__ float sg[1024];
    for (int idx = t; idx < 1024; idx += 256)
        sg[idx] = g[(size_t)b * NG + goff + idx];
    float acc[4][4];
#pragma unroll
    for (int r = 0; r < 4; ++r)
#pragma unroll
        for (int c = 0; c < 4; ++c) acc[r][c] = 0.f;
    int i0 = (t & 15) * 4, j0 = (t >> 4) * 4;
    int m = t >> 2, gs = (t & 3) * 8;
    __syncthreads();
    for (int ch = 0; ch < 32; ++ch) {
        const float* Ar = A + (size_t)m * NG + goff + ch * 32 + gs;
        float4 v0 = *(const float4*)Ar;
        float4 v1 = *(const float4*)(Ar + 4);
        __syncthreads();   // protect previous chunk's reads
        sA[(gs + 0) * 64 + m] = v0.x; sAg[(gs + 0) * 64 + m] = v0.x * sg[ch * 32 + gs + 0];
        sA[(gs + 1) * 64 + m] = v0.y; sAg[(gs + 1) * 64 + m] = v0.y * sg[ch * 32 + gs + 1];
        sA[(gs + 2) * 64 + m] = v0.z; sAg[(gs + 2) * 64 + m] = v0.z * sg[ch * 32 + gs + 2];
        sA[(gs + 3) * 64 + m] = v0.w; sAg[(gs + 3) * 64 + m] = v0.w * sg[ch * 32 + gs + 3];
        sA[(gs + 4) * 64 + m] = v1.x; sAg[(gs + 4) * 64 + m] = v1.x * sg[ch * 32 + gs + 4];
        sA[(gs + 5) * 64 + m] = v1.y; sAg[(gs + 5) * 64 + m] = v1.y * sg[ch * 32 + gs + 5];
        sA[(gs + 6) * 64 + m] = v1.z; sAg[(gs + 6) * 64 + m] = v1.z * sg[ch * 32 + gs + 6];
        sA[(gs + 7) * 64 + m] = v1.w; sAg[(gs + 7) * 64 + m] = v1.w * sg[ch * 32 + gs + 7];
        __syncthreads();
#pragma unroll
        for (int gg = 0; gg < 32; ++gg) {
            float4 av = *(const float4*)&sAg[gg * 64 + i0];
            float4 bv = *(const float4*)&sA[gg * 64 + j0];
            acc[0][0] += av.x * bv.x; acc[0][1] += av.x * bv.y;
            acc[0][2] += av.x * bv.z; acc[0][3] += av.x * bv.w;
            acc[1][0] += av.y * bv.x; acc[1][1] += av.y * bv.y;
            acc[1][2] += av.y * bv.z; acc[1][3] += av.y * bv.w;
            acc[2][0] += av.z * bv.x; acc[2][1] += av.z * bv.y;
            acc[2][2] += av.z * bv.z; acc[2][3] += av.z * bv.w;
            acc[3][0] += av.w * bv.x; acc[3][1] += av.w * bv.y;
            acc[3][2] += av.w * bv.z; acc[3][3] += av.w * bv.w;
        }
    }
    float* dst = (half ? p1 : p0) + (size_t)b * 4096;
#pragma unroll
    for (int r = 0; r < 4; ++r)
#pragma unroll
        for (int c = 0; c < 4; ++c)
            dst[(i0 + r) * 64 + j0 + c] = acc[r][c];
}

// Sum partial covs + 0.1 I, Gauss-Jordan invert with partial pivoting,
// then S -> Sbuf, M = S*D*S -> Mbuf.
__global__ __launch_bounds__(256) void k_inv(const float* __restrict__ Dws,
                                             float* __restrict__ Sbuf,
                                             float* __restrict__ Mbuf) {
    __shared__ float aug[64 * 131];  // stride 131: (3i + j) % 32 -> 2-way max
    __shared__ float Dl[64 * 65];
    __shared__ float Pl[64 * 65];
    __shared__ int pivsh;
    __shared__ float pvsh;
    int b = blockIdx.x, t = threadIdx.x;
    const float* s0 = Sbuf + (size_t)b * 4096;
    const float* s1 = Mbuf + (size_t)b * 4096;
    const float* Dg = Dws + (size_t)b * 4096;
    for (int idx = t; idx < 4096; idx += 256) {
        int i = idx >> 6, j = idx & 63;
        float v = s0[idx] + s1[idx];
        if (i == j) v += 0.1f;
        aug[i * 131 + j] = v;
        aug[i * 131 + 64 + j] = (i == j) ? 1.0f : 0.0f;
        Dl[i * 65 + j] = Dg[idx];
    }
    __syncthreads();
    for (int k = 0; k < 64; ++k) {
        // pivot search over rows >= k (wave 0 only)
        if (t < 64) {
            float v = (t >= k) ? fabsf(aug[t * 131 + k]) : -1.0f;
            int ix = t;
#pragma unroll
            for (int off = 32; off > 0; off >>= 1) {
                float ov = __shfl_down(v, off, 64);
                int oi = __shfl_down(ix, off, 64);
                if (ov > v) { v = ov; ix = oi; }
            }
            if (t == 0) { pivsh = ix; pvsh = aug[ix * 131 + k]; }
        }
        __syncthreads();
        int p = pivsh;
        float rinv = 1.0f / pvsh;
        // fused swap + scale: each column owned by exactly one thread
        if (t < 128) {
            float vk = aug[k * 131 + t];
            if (p != k) { float vp = aug[p * 131 + t]; aug[p * 131 + t] = vk; vk = vp; }
            aug[k * 131 + t] = vk * rinv;
        }
        __syncthreads();
        // eliminate all rows != k; skip cols <= k in left half (never read again,
        // and skipping col k avoids a read/write race on the f values)
        int row = t & 63, cg = t >> 6;
        if (row != k) {
            float f = aug[row * 131 + k];
#pragma unroll
            for (int jj = 0; jj < 32; ++jj) {
                int j = cg * 32 + jj;
                float v = aug[row * 131 + j] - f * aug[k * 131 + j];
                if (j >= 64 || j > k) aug[row * 131 + j] = v;
            }
        }
        __syncthreads();
    }
    // write S
    for (int idx = t; idx < 4096; idx += 256)
        Sbuf[(size_t)b * 4096 + idx] = aug[(idx >> 6) * 131 + 64 + (idx & 63)];
    // P = D * S
    int i0 = (t & 15) * 4, j0 = (t >> 4) * 4;
    float pacc[4][4];
#pragma unroll
    for (int r = 0; r < 4; ++r)
#pragma unroll
        for (int c = 0; c < 4; ++c) pacc[r][c] = 0.f;
    for (int k = 0; k < 64; ++k) {
        float dv[4], sv[4];
#pragma unroll
        for (int r = 0; r < 4; ++r) dv[r] = Dl[(i0 + r) * 65 + k];
#pragma unroll
        for (int c = 0; c < 4; ++c) sv[c] = aug[k * 131 + 64 + j0 + c];
#pragma unroll
        for (int r = 0; r < 4; ++r)
#pragma unroll
            for (int c = 0; c < 4; ++c) pacc[r][c] += dv[r] * sv[c];
    }
#pragma unroll
    for (int r = 0; r < 4; ++r)
#pragma unroll
        for (int c = 0; c < 4; ++c) Pl[(i0 + r) * 65 + j0 + c] = pacc[r][c];
    __syncthreads();
    // M = S * P
    float macc[4][4];
#pragma unroll
    for (int r = 0; r < 4; ++r)
#pragma unroll
        for (int c = 0; c < 4; ++c) macc[r][c] = 0.f;
    for (int k = 0; k < 64; ++k) {
        float sv[4], pv[4];
#pragma unroll
        for (int r = 0; r < 4; ++r) sv[r] = aug[(i0 + r) * 131 + 64 + k];
#pragma unroll
        for (int c = 0; c < 4; ++c) pv[c] = Pl[k * 65 + j0 + c];
#pragma unroll
        for (int r = 0; r < 4; ++r)
#pragma unroll
            for (int c = 0; c < 4; ++c) macc[r][c] += sv[r] * pv[c];
    }
#pragma unroll
    for (int r = 0; r < 4; ++r)
#pragma unroll
        for (int c = 0; c < 4; ++c)
            Mbuf[(size_t)b * 4096 + (i0 + r) * 64 + j0 + c] = macc[r][c];
}

// Features: T2 = |a^T S a|, T1 = a^T M a  (a = A[:,g]); S/M rows are
// block-uniform -> scalar-load friendly.
__global__ __launch_bounds__(256) void k_feat(const float* __restrict__ A,
                                              const float* __restrict__ Sbuf,
                                              const float* __restrict__ Mbuf,
                                              float* __restrict__ T1,
                                              float* __restrict__ T2) {
    int b = blockIdx.x >> 2, q = blockIdx.x & 3, t = threadIdx.x;
    const float* S = Sbuf + (size_t)b * 4096;
    const float* Mx = Mbuf + (size_t)b * 4096;
    for (int rep = 0; rep < 2; ++rep) {
        int gidx = q * 512 + rep * 256 + t;
        float a[64];
#pragma unroll
        for (int mI = 0; mI < 64; ++mI) a[mI] = A[(size_t)mI * NG + gidx];
        float accS = 0.f, accM = 0.f;
        for (int i = 0; i < 64; ++i) {
            const float4* Sr = (const float4*)(S + i * 64);
            const float4* Mr = (const float4*)(Mx + i * 64);
            float s0 = 0.f, s1 = 0.f, s2 = 0.f, s3 = 0.f;
            float m0 = 0.f, m1 = 0.f, m2 = 0.f, m3 = 0.f;
#pragma unroll
            for (int jc = 0; jc < 16; ++jc) {
                float4 sv = Sr[jc];
                float4 mv = Mr[jc];
                s0 += sv.x * a[jc * 4 + 0]; s1 += sv.y * a[jc * 4 + 1];
                s2 += sv.z * a[jc * 4 + 2]; s3 += sv.w * a[jc * 4 + 3];
                m0 += mv.x * a[jc * 4 + 0]; m1 += mv.y * a[jc * 4 + 1];
                m2 += mv.z * a[jc * 4 + 2]; m3 += mv.w * a[jc * 4 + 3];
            }
            float ai = A[(size_t)i * NG + gidx];  // reload: avoids dynamic reg index
            accS += ai * ((s0 + s1) + (s2 + s3));
            accM += ai * ((m0 + m1) + (m2 + m3));
        }
        T2[(size_t)b * NG + gidx] = fabsf(accS);
        T1[(size_t)b * NG + gidx] = accM;   // D already scaled by 1/NT
    }
}

// Per-gridpoint MLP; g-major blocking so weights are read once per iteration.
__global__ __launch_bounds__(256) void k_mlp(const float* __restrict__ T1,
                                             const float* __restrict__ T2,
                                             const float* __restrict__ gcur,
                                             const float* __restrict__ W1,
                                             const float* __restrict__ b1,
                                             const float* __restrict__ W2,
                                             const float* __restrict__ b2,
                                             const float* __restrict__ W3,
                                             const float* __restrict__ b3,
                                             int it, float* __restrict__ out) {
    // per-g LDS block: [0,96) W1, [96,128) b1, [128,1152) W2, [1152,1184) b2,
    // [1184,1216) W3, [1216] b3, stride 1220 (bank spread, 16B aligned)
    __shared__ float w[8 * 1220];
    int t = threadIdx.x, g0 = blockIdx.x * 8;
    for (int gl = 0; gl < 8; ++gl) {
        size_t gi = (size_t)it * NG + g0 + gl;
        float* wd = &w[gl * 1220];
        if (t < 96) wd[t] = W1[gi * 96 + t];
        else if (t < 128) wd[t] = b1[gi * 32 + (t - 96)];
        const float* w2 = W2 + gi * 1024;
#pragma unroll
        for (int u = 0; u < 4; ++u) wd[128 + u * 256 + t] = w2[u * 256 + t];
        if (t < 32) wd[1152 + t] = b2[gi * 32 + t];
        else if (t < 64) wd[1184 + (t - 32)] = W3[gi * 32 + (t - 32)];
        else if (t == 64) wd[1216] = b3[gi];
    }
    __syncthreads();
    int gl = t & 7, gg = g0 + gl;
    const float* wd = &w[gl * 1220];
    for (int bp = 0; bp < 4; ++bp) {
        int bb = (t >> 3) + bp * 32;
        size_t xo = (size_t)bb * NG + gg;
        float x0 = T1[xo], x1 = T2[xo], x2 = gcur[xo];
        float h1[32];
#pragma unroll
        for (int k = 0; k < 32; k += 4) {
            float4 wa = *(const float4*)(wd + k);
            float4 wb = *(const float4*)(wd + 32 + k);
            float4 wc = *(const float4*)(wd + 64 + k);
            float4 bv = *(const float4*)(wd + 96 + k);
            h1[k + 0] = fmaxf(0.f, x0 * wa.x + x1 * wb.x + x2 * wc.x + bv.x);
            h1[k + 1] = fmaxf(0.f, x0 * wa.y + x1 * wb.y + x2 * wc.y + bv.y);
            h1[k + 2] = fmaxf(0.f, x0 * wa.z + x1 * wb.z + x2 * wc.z + bv.z);
            h1[k + 3] = fmaxf(0.f, x0 * wa.w + x1 * wb.w + x2 * wc.w + bv.w);
        }
        float acc = wd[1216];
#pragma unroll
        for (int k = 0; k < 32; k += 4) {
            float4 hb = *(const float4*)(wd + 1152 + k);
            float v0 = hb.x, v1 = hb.y, v2 = hb.z, v3 = hb.w;
#pragma unroll
            for (int j = 0; j < 32; ++j) {
                float4 w2v = *(const float4*)(wd + 128 + j * 32 + k);
                v0 += h1[j] * w2v.x; v1 += h1[j] * w2v.y;
                v2 += h1[j] * w2v.z; v3 += h1[j] * w2v.w;
            }
            float4 w3v = *(const float4*)(wd + 1184 + k);
            acc += fmaxf(0.f, v0) * w3v.x + fmaxf(0.f, v1) * w3v.y +
                   fmaxf(0.f, v2) * w3v.z + fmaxf(0.f, v3) * w3v.w;
        }
        out[xo] = acc;
    }
}

extern "C" void kernel_launch(void* const* d_in, const int* in_sizes, int n_in,
                              void* d_out, int out_size, void* d_ws, size_t ws_size,
                              hipStream_t stream) {
    const float* data = (const float*)d_in[0];
    const float* A    = (const float*)d_in[1];
    const float* W1   = (const float*)d_in[2];
    const float* b1   = (const float*)d_in[3];
    const float* W2   = (const float*)d_in[4];
    const float* b2   = (const float*)d_in[5];
    const float* W3   = (const float*)d_in[6];
    const float* b3   = (const float*)d_in[7];
    float* out = (float*)d_out;
    float* ws = (float*)d_ws;

    float* D  = ws;
    float* S  = ws + 524288;
    float* Mx = ws + 1048576;
    float* T1 = ws + 1572864;
    float* T2 = ws + 1835008;
    float* gA = ws + 2097152;
    float* gB = ws + 2359296;

    k_init<<<dim3(1024), dim3(256), 0, stream>>>(gA);
    k_D<<<dim3(128), dim3(256), 0, stream>>>(data, D);

    float* gc = gA;
    float* gn = gB;
    for (int it = 0; it < 3; ++it) {
        k_cov<<<dim3(256), dim3(256), 0, stream>>>(A, gc, S, Mx);
        k_inv<<<dim3(128), dim3(256), 0, stream>>>(D, S, Mx);
        k_feat<<<dim3(512), dim3(256), 0, stream>>>(A, S, Mx, T1, T2);
        float* dst = (it == 2) ? out : gn;
        k_mlp<<<dim3(256), dim3(256), 0, stream>>>(T1, T2, gc, W1, b1, W2, b2, W3, b3, it, dst);
        float* tmp = gc; gc = gn; gn = tmp;
    }
}

// Round 2
// 960.430 us; speedup vs baseline: 1.5736x; 1.5736x over previous
//
#include <hip/hip_runtime.h>

// Problem constants
#define NB 128      // batch
#define NM 64       // sensors
#define NT 128      // snapshots
#define NG 2048     // gridpoints
#define NH 32       // hidden
// VAR_NOISE = 0.1f

// ---------------------------------------------------------------------------
// Workspace layout (floats):
//  D   [128*64*64]   off 0
//  P0  [128*64*64]   off 524288   (cov partial q0; becomes S after k_inv)
//  P1  [128*64*64]   off 1048576  (cov partial q1; becomes M after k_inv)
//  P2  [128*64*64]   off 1572864  (cov partial q2)
//  P3  [128*64*64]   off 2097152  (cov partial q3)
//  T1  [128*2048]    off 2621440
//  T2  [128*2048]    off 2883584
//  gA  [128*2048]    off 3145728
//  gB  [128*2048]    off 3407872
//  total 3670016 floats = 14 MB
// ---------------------------------------------------------------------------

__global__ __launch_bounds__(256) void k_init(float* __restrict__ g) {
    g[blockIdx.x * 256 + threadIdx.x] = 1.0f;
}

// D[b] = data[b] * data[b]^T / NT    (once per call; data constant)
__global__ __launch_bounds__(256) void k_D(const float* __restrict__ data,
                                           float* __restrict__ D) {
    __shared__ float sd[64 * 133];
    int b = blockIdx.x, t = threadIdx.x;
    const float* db = data + (size_t)b * 8192;
    for (int idx = t; idx < 8192; idx += 256)
        sd[(idx >> 7) * 133 + (idx & 127)] = db[idx];
    __syncthreads();
    int i0 = (t & 15) * 4, j0 = (t >> 4) * 4;
    float acc[4][4];
#pragma unroll
    for (int r = 0; r < 4; ++r)
#pragma unroll
        for (int c = 0; c < 4; ++c) acc[r][c] = 0.f;
    for (int tt = 0; tt < 128; ++tt) {
        float av[4], bv[4];
#pragma unroll
        for (int r = 0; r < 4; ++r) av[r] = sd[(i0 + r) * 133 + tt];
#pragma unroll
        for (int c = 0; c < 4; ++c) bv[c] = sd[(j0 + c) * 133 + tt];
#pragma unroll
        for (int r = 0; r < 4; ++r)
#pragma unroll
            for (int c = 0; c < 4; ++c) acc[r][c] += av[r] * bv[c];
    }
    float* Db = D + (size_t)b * 4096;
#pragma unroll
    for (int r = 0; r < 4; ++r)
#pragma unroll
        for (int c = 0; c < 4; ++c)
            Db[(i0 + r) * 64 + j0 + c] = acc[r][c] * (1.0f / 128.0f);
}

// Partial covariance: block (b, quarter q) accumulates over 512 g's into
// partial buffer q; the four partials are summed in k_inv.
__global__ __launch_bounds__(256) void k_cov(const float* __restrict__ A,
                                             const float* __restrict__ g,
                                             float* __restrict__ p0,
                                             float* __restrict__ p1,
                                             float* __restrict__ p2,
                                             float* __restrict__ p3) {
    int b = blockIdx.x >> 2, q = blockIdx.x & 3, t = threadIdx.x;
    int goff = q * 512;
    __shared__ float sA[32 * 64];    // [gg][m]
    __shared__ float sAg[32 * 64];   // scaled by gamma
    __shared__ float sg[512];
    for (int idx = t; idx < 512; idx += 256)
        sg[idx] = g[(size_t)b * NG + goff + idx];
    float acc[4][4];
#pragma unroll
    for (int r = 0; r < 4; ++r)
#pragma unroll
        for (int c = 0; c < 4; ++c) acc[r][c] = 0.f;
    int i0 = (t & 15) * 4, j0 = (t >> 4) * 4;
    int m = t >> 2, gs = (t & 3) * 8;
    __syncthreads();
    for (int ch = 0; ch < 16; ++ch) {
        const float* Ar = A + (size_t)m * NG + goff + ch * 32 + gs;
        float4 v0 = *(const float4*)Ar;
        float4 v1 = *(const float4*)(Ar + 4);
        __syncthreads();   // protect previous chunk's reads
        sA[(gs + 0) * 64 + m] = v0.x; sAg[(gs + 0) * 64 + m] = v0.x * sg[ch * 32 + gs + 0];
        sA[(gs + 1) * 64 + m] = v0.y; sAg[(gs + 1) * 64 + m] = v0.y * sg[ch * 32 + gs + 1];
        sA[(gs + 2) * 64 + m] = v0.z; sAg[(gs + 2) * 64 + m] = v0.z * sg[ch * 32 + gs + 2];
        sA[(gs + 3) * 64 + m] = v0.w; sAg[(gs + 3) * 64 + m] = v0.w * sg[ch * 32 + gs + 3];
        sA[(gs + 4) * 64 + m] = v1.x; sAg[(gs + 4) * 64 + m] = v1.x * sg[ch * 32 + gs + 4];
        sA[(gs + 5) * 64 + m] = v1.y; sAg[(gs + 5) * 64 + m] = v1.y * sg[ch * 32 + gs + 5];
        sA[(gs + 6) * 64 + m] = v1.z; sAg[(gs + 6) * 64 + m] = v1.z * sg[ch * 32 + gs + 6];
        sA[(gs + 7) * 64 + m] = v1.w; sAg[(gs + 7) * 64 + m] = v1.w * sg[ch * 32 + gs + 7];
        __syncthreads();
#pragma unroll
        for (int gg = 0; gg < 32; ++gg) {
            float4 av = *(const float4*)&sAg[gg * 64 + i0];
            float4 bv = *(const float4*)&sA[gg * 64 + j0];
            acc[0][0] += av.x * bv.x; acc[0][1] += av.x * bv.y;
            acc[0][2] += av.x * bv.z; acc[0][3] += av.x * bv.w;
            acc[1][0] += av.y * bv.x; acc[1][1] += av.y * bv.y;
            acc[1][2] += av.y * bv.z; acc[1][3] += av.y * bv.w;
            acc[2][0] += av.z * bv.x; acc[2][1] += av.z * bv.y;
            acc[2][2] += av.z * bv.z; acc[2][3] += av.z * bv.w;
            acc[3][0] += av.w * bv.x; acc[3][1] += av.w * bv.y;
            acc[3][2] += av.w * bv.z; acc[3][3] += av.w * bv.w;
        }
    }
    float* dst = (q == 0 ? p0 : q == 1 ? p1 : q == 2 ? p2 : p3) + (size_t)b * 4096;
#pragma unroll
    for (int r = 0; r < 4; ++r)
#pragma unroll
        for (int c = 0; c < 4; ++c)
            dst[(i0 + r) * 64 + j0 + c] = acc[r][c];
}

// Sum partial covs + 0.1 I, Gauss-Jordan invert with partial pivoting,
// then S -> Sbuf(=P0), M = S*D*S -> Mbuf(=P1).
__global__ __launch_bounds__(256) void k_inv(const float* __restrict__ Dws,
                                             float* __restrict__ Sbuf,
                                             float* __restrict__ Mbuf,
                                             const float* __restrict__ p2,
                                             const float* __restrict__ p3) {
    __shared__ float aug[64 * 131];
    __shared__ float Dl[64 * 65];
    __shared__ float Pl[64 * 65];
    __shared__ int pivsh;
    __shared__ float pvsh;
    int b = blockIdx.x, t = threadIdx.x;
    const float* s0 = Sbuf + (size_t)b * 4096;
    const float* s1 = Mbuf + (size_t)b * 4096;
    const float* s2 = p2 + (size_t)b * 4096;
    const float* s3 = p3 + (size_t)b * 4096;
    const float* Dg = Dws + (size_t)b * 4096;
    for (int idx = t; idx < 4096; idx += 256) {
        int i = idx >> 6, j = idx & 63;
        float v = (s0[idx] + s1[idx]) + (s2[idx] + s3[idx]);
        if (i == j) v += 0.1f;
        aug[i * 131 + j] = v;
        aug[i * 131 + 64 + j] = (i == j) ? 1.0f : 0.0f;
        Dl[i * 65 + j] = Dg[idx];
    }
    __syncthreads();
    for (int k = 0; k < 64; ++k) {
        if (t < 64) {
            float v = (t >= k) ? fabsf(aug[t * 131 + k]) : -1.0f;
            int ix = t;
#pragma unroll
            for (int off = 32; off > 0; off >>= 1) {
                float ov = __shfl_down(v, off, 64);
                int oi = __shfl_down(ix, off, 64);
                if (ov > v) { v = ov; ix = oi; }
            }
            if (t == 0) { pivsh = ix; pvsh = aug[ix * 131 + k]; }
        }
        __syncthreads();
        int p = pivsh;
        float rinv = 1.0f / pvsh;
        if (t < 128) {
            float vk = aug[k * 131 + t];
            if (p != k) { float vp = aug[p * 131 + t]; aug[p * 131 + t] = vk; vk = vp; }
            aug[k * 131 + t] = vk * rinv;
        }
        __syncthreads();
        int row = t & 63, cg = t >> 6;
        if (row != k) {
            float f = aug[row * 131 + k];
#pragma unroll
            for (int jj = 0; jj < 32; ++jj) {
                int j = cg * 32 + jj;
                float v = aug[row * 131 + j] - f * aug[k * 131 + j];
                if (j >= 64 || j > k) aug[row * 131 + j] = v;
            }
        }
        __syncthreads();
    }
    for (int idx = t; idx < 4096; idx += 256)
        Sbuf[(size_t)b * 4096 + idx] = aug[(idx >> 6) * 131 + 64 + (idx & 63)];
    // P = D * S
    int i0 = (t & 15) * 4, j0 = (t >> 4) * 4;
    float pacc[4][4];
#pragma unroll
    for (int r = 0; r < 4; ++r)
#pragma unroll
        for (int c = 0; c < 4; ++c) pacc[r][c] = 0.f;
    for (int k = 0; k < 64; ++k) {
        float dv[4], sv[4];
#pragma unroll
        for (int r = 0; r < 4; ++r) dv[r] = Dl[(i0 + r) * 65 + k];
#pragma unroll
        for (int c = 0; c < 4; ++c) sv[c] = aug[k * 131 + 64 + j0 + c];
#pragma unroll
        for (int r = 0; r < 4; ++r)
#pragma unroll
            for (int c = 0; c < 4; ++c) pacc[r][c] += dv[r] * sv[c];
    }
#pragma unroll
    for (int r = 0; r < 4; ++r)
#pragma unroll
        for (int c = 0; c < 4; ++c) Pl[(i0 + r) * 65 + j0 + c] = pacc[r][c];
    __syncthreads();
    // M = S * P
    float macc[4][4];
#pragma unroll
    for (int r = 0; r < 4; ++r)
#pragma unroll
        for (int c = 0; c < 4; ++c) macc[r][c] = 0.f;
    for (int k = 0; k < 64; ++k) {
        float sv[4], pv[4];
#pragma unroll
        for (int r = 0; r < 4; ++r) sv[r] = aug[(i0 + r) * 131 + 64 + k];
#pragma unroll
        for (int c = 0; c < 4; ++c) pv[c] = Pl[k * 65 + j0 + c];
#pragma unroll
        for (int r = 0; r < 4; ++r)
#pragma unroll
            for (int c = 0; c < 4; ++c) macc[r][c] += sv[r] * pv[c];
    }
#pragma unroll
    for (int r = 0; r < 4; ++r)
#pragma unroll
        for (int c = 0; c < 4; ++c)
            Mbuf[(size_t)b * 4096 + (i0 + r) * 64 + j0 + c] = macc[r][c];
}

// Features v2: T2 = |a^T S a|, T1 = a^T M a.
// S,M staged in LDS (broadcast ds_read_b128); 2 g's per thread, i-range
// split 2-way; block = (b, 256-g tile), grid = 128*8 = 1024.
__global__ __launch_bounds__(256) void k_feat(const float* __restrict__ A,
                                              const float* __restrict__ Sbuf,
                                              const float* __restrict__ Mbuf,
                                              float* __restrict__ T1,
                                              float* __restrict__ T2) {
    __shared__ float sS[4096];
    __shared__ float sM[4096];
    int t = threadIdx.x;
    int b = blockIdx.x >> 3, tile = blockIdx.x & 7;
    {
        const float4* S4 = (const float4*)(Sbuf + (size_t)b * 4096);
        const float4* M4 = (const float4*)(Mbuf + (size_t)b * 4096);
        float4* sS4 = (float4*)sS;
        float4* sM4 = (float4*)sM;
#pragma unroll
        for (int u = 0; u < 4; ++u) {
            sS4[u * 256 + t] = S4[u * 256 + t];
            sM4[u * 256 + t] = M4[u * 256 + t];
        }
    }
    int gl = t & 127, ih = t >> 7;
    int g = tile * 256 + gl;            // second g is g+128
    float a0[64], a1[64];
#pragma unroll
    for (int m = 0; m < 64; ++m) {
        a0[m] = A[(size_t)m * NG + g];
        a1[m] = A[(size_t)m * NG + g + 128];
    }
    __syncthreads();
    float accS0 = 0.f, accS1 = 0.f, accM0 = 0.f, accM1 = 0.f;
    int ibase = ih * 32;
#pragma unroll 4
    for (int ii = 0; ii < 32; ++ii) {
        int i = ibase + ii;
        const float4* Sr = (const float4*)(sS + i * 64);
        const float4* Mr = (const float4*)(sM + i * 64);
        float sd0 = 0.f, sd1 = 0.f, md0 = 0.f, md1 = 0.f;
#pragma unroll
        for (int jc = 0; jc < 16; ++jc) {
            float4 sv = Sr[jc];
            float4 mv = Mr[jc];
            sd0 += sv.x * a0[4 * jc] + sv.y * a0[4 * jc + 1] +
                   sv.z * a0[4 * jc + 2] + sv.w * a0[4 * jc + 3];
            sd1 += sv.x * a1[4 * jc] + sv.y * a1[4 * jc + 1] +
                   sv.z * a1[4 * jc + 2] + sv.w * a1[4 * jc + 3];
            md0 += mv.x * a0[4 * jc] + mv.y * a0[4 * jc + 1] +
                   mv.z * a0[4 * jc + 2] + mv.w * a0[4 * jc + 3];
            md1 += mv.x * a1[4 * jc] + mv.y * a1[4 * jc + 1] +
                   mv.z * a1[4 * jc + 2] + mv.w * a1[4 * jc + 3];
        }
        float ai0 = A[(size_t)i * NG + g];
        float ai1 = A[(size_t)i * NG + g + 128];
        accS0 += ai0 * sd0; accS1 += ai1 * sd1;
        accM0 += ai0 * md0; accM1 += ai1 * md1;
    }
    __syncthreads();              // all reads of sS done; reuse for partials
    float4* part = (float4*)sS;   // [256] float4: (S0,S1,M0,M1) per thread
    part[t] = make_float4(accS0, accS1, accM0, accM1);
    __syncthreads();
    if (t < 128) {
        float4 q0 = part[t], q1 = part[t + 128];
        int go = (size_t)0 + tile * 256 + t;
        size_t base = (size_t)b * NG + go;
        T2[base]       = fabsf(q0.x + q1.x);
        T2[base + 128] = fabsf(q0.y + q1.y);
        T1[base]       = q0.z + q1.z;
        T1[base + 128] = q0.w + q1.w;
    }
}

// Per-gridpoint MLP; g-major blocking so weights are read once per iteration.
__global__ __launch_bounds__(256) void k_mlp(const float* __restrict__ T1,
                                             const float* __restrict__ T2,
                                             const float* __restrict__ gcur,
                                             const float* __restrict__ W1,
                                             const float* __restrict__ b1,
                                             const float* __restrict__ W2,
                                             const float* __restrict__ b2,
                                             const float* __restrict__ W3,
                                             const float* __restrict__ b3,
                                             int it, float* __restrict__ out) {
    __shared__ float w[8 * 1220];
    int t = threadIdx.x, g0 = blockIdx.x * 8;
    for (int gl = 0; gl < 8; ++gl) {
        size_t gi = (size_t)it * NG + g0 + gl;
        float* wd = &w[gl * 1220];
        if (t < 96) wd[t] = W1[gi * 96 + t];
        else if (t < 128) wd[t] = b1[gi * 32 + (t - 96)];
        const float* w2 = W2 + gi * 1024;
#pragma unroll
        for (int u = 0; u < 4; ++u) wd[128 + u * 256 + t] = w2[u * 256 + t];
        if (t < 32) wd[1152 + t] = b2[gi * 32 + t];
        else if (t < 64) wd[1184 + (t - 32)] = W3[gi * 32 + (t - 32)];
        else if (t == 64) wd[1216] = b3[gi];
    }
    __syncthreads();
    int gl = t & 7, gg = g0 + gl;
    const float* wd = &w[gl * 1220];
    for (int bp = 0; bp < 4; ++bp) {
        int bb = (t >> 3) + bp * 32;
        size_t xo = (size_t)bb * NG + gg;
        float x0 = T1[xo], x1 = T2[xo], x2 = gcur[xo];
        float h1[32];
#pragma unroll
        for (int k = 0; k < 32; k += 4) {
            float4 wa = *(const float4*)(wd + k);
            float4 wb = *(const float4*)(wd + 32 + k);
            float4 wc = *(const float4*)(wd + 64 + k);
            float4 bv = *(const float4*)(wd + 96 + k);
            h1[k + 0] = fmaxf(0.f, x0 * wa.x + x1 * wb.x + x2 * wc.x + bv.x);
            h1[k + 1] = fmaxf(0.f, x0 * wa.y + x1 * wb.y + x2 * wc.y + bv.y);
            h1[k + 2] = fmaxf(0.f, x0 * wa.z + x1 * wb.z + x2 * wc.z + bv.z);
            h1[k + 3] = fmaxf(0.f, x0 * wa.w + x1 * wb.w + x2 * wc.w + bv.w);
        }
        float acc = wd[1216];
#pragma unroll
        for (int k = 0; k < 32; k += 4) {
            float4 hb = *(const float4*)(wd + 1152 + k);
            float v0 = hb.x, v1 = hb.y, v2 = hb.z, v3 = hb.w;
#pragma unroll
            for (int j = 0; j < 32; ++j) {
                float4 w2v = *(const float4*)(wd + 128 + j * 32 + k);
                v0 += h1[j] * w2v.x; v1 += h1[j] * w2v.y;
                v2 += h1[j] * w2v.z; v3 += h1[j] * w2v.w;
            }
            float4 w3v = *(const float4*)(wd + 1184 + k);
            acc += fmaxf(0.f, v0) * w3v.x + fmaxf(0.f, v1) * w3v.y +
                   fmaxf(0.f, v2) * w3v.z + fmaxf(0.f, v3) * w3v.w;
        }
        out[xo] = acc;
    }
}

extern "C" void kernel_launch(void* const* d_in, const int* in_sizes, int n_in,
                              void* d_out, int out_size, void* d_ws, size_t ws_size,
                              hipStream_t stream) {
    const float* data = (const float*)d_in[0];
    const float* A    = (const float*)d_in[1];
    const float* W1   = (const float*)d_in[2];
    const float* b1   = (const float*)d_in[3];
    const float* W2   = (const float*)d_in[4];
    const float* b2   = (const float*)d_in[5];
    const float* W3   = (const float*)d_in[6];
    const float* b3   = (const float*)d_in[7];
    float* out = (float*)d_out;
    float* ws = (float*)d_ws;

    float* D  = ws;
    float* P0 = ws + 524288;    // becomes S
    float* P1 = ws + 1048576;   // becomes M
    float* P2 = ws + 1572864;
    float* P3 = ws + 2097152;
    float* T1 = ws + 2621440;
    float* T2 = ws + 2883584;
    float* gA = ws + 3145728;
    float* gB = ws + 3407872;

    k_init<<<dim3(1024), dim3(256), 0, stream>>>(gA);
    k_D<<<dim3(128), dim3(256), 0, stream>>>(data, D);

    float* gc = gA;
    float* gn = gB;
    for (int it = 0; it < 3; ++it) {
        k_cov<<<dim3(512), dim3(256), 0, stream>>>(A, gc, P0, P1, P2, P3);
        k_inv<<<dim3(128), dim3(256), 0, stream>>>(D, P0, P1, P2, P3);
        k_feat<<<dim3(1024), dim3(256), 0, stream>>>(A, P0, P1, T1, T2);
        float* dst = (it == 2) ? out : gn;
        k_mlp<<<dim3(256), dim3(256), 0, stream>>>(T1, T2, gc, W1, b1, W2, b2, W3, b3, it, dst);
        float* tmp = gc; gc = gn; gn = tmp;
    }
}